// Round 6
// baseline (112.259 us; speedup 1.0000x reference)
//
#include <hip/hip_runtime.h>
#include <hip/hip_bf16.h>
#include <stdint.h>

#define BATCH 32
#define SEQT  1024
#define INF   1024
#define OUTF  512
#define MROWS (BATCH * SEQT)   // 32768

typedef __attribute__((ext_vector_type(8))) short short8;
typedef __attribute__((ext_vector_type(4))) float f32x4;

__device__ __forceinline__ short f2bf(float f) {
    return (short)__builtin_bit_cast(unsigned short, __float2bfloat16(f));
}

// async global->LDS DMA, 16B per lane, LDS dest = wave-uniform base + lane*16
__device__ __forceinline__ void gll16(const float* g, float* l) {
    __builtin_amdgcn_global_load_lds(
        (const __attribute__((address_space(1))) unsigned int*)g,
        (__attribute__((address_space(3))) unsigned int*)l, 16, 0, 0);
}

// ---------------------------------------------------------------------------
// GEMM: cur[m,o] = bf16( sum_k X[m,k]*W[o,k] + bias[o] )
// 256x256 tile, BK=32, 512 threads (4x2 waves of 64x128 each), grid=256=1/CU.
// fp32 tiles DMA'd to LDS via global_load_lds (linear dest, pre-swizzled
// global source granule); read-side fp32->bf16 cvt.
// COUNTED-vmcnt schedule (T3+T4): per K-step
//   STAGE(next) ; s_waitcnt vmcnt(8) ; s_barrier ; reads+MFMA ; s_barrier
// -> next-buffer DMAs stay in flight ACROSS barriers (never drain to 0 in
// the main loop); last iteration peels to vmcnt(0).
// ---------------------------------------------------------------------------
__global__ __launch_bounds__(512, 2) void gemm_bf16_kernel(
    const float* __restrict__ X, const float* __restrict__ W,
    const float* __restrict__ bias, __hip_bfloat16* __restrict__ C) {
    __shared__ float lds_f[32768];   // 128 KB: [buf][A 8192 f | B 8192 f]

    const int tid = threadIdx.x;
    const int bid = blockIdx.x;
    // XCD pairing: xcd = bid&7 gets 16 m-tiles x both n-tiles.
    const int xcd = bid & 7;
    const int ii  = bid >> 3;                 // 0..31
    const int mt  = (xcd << 4) + (ii >> 1);   // 0..127
    const int nt  = ii & 1;
    const int m0 = mt << 8;
    const int o0 = nt << 8;

    const int wv   = tid >> 6;
    const int lane = tid & 63;
    const int wr = wv >> 1;       // 0..3  (64-row slab)
    const int wc = wv & 1;        // 0..1  (128-col slab)
    const int r0 = lane & 15;
    const int lg = lane >> 4;     // k-group q = 0..3

    // staging: granule g -> row r=g>>3, dest slot g&7 (linear LDS),
    // src slot s' = (g&7)^(r&7) (pre-swizzled global source).
    const float* srcA[4];
    const float* srcB[4];
    int dstf[4];
#pragma unroll
    for (int j = 0; j < 4; ++j) {
        const int g = (j << 9) + tid;
        const int r = g >> 3;
        const int s = (g & 7) ^ (r & 7);
        dstf[j] = g << 2;
        srcA[j] = X + (size_t)(m0 + r) * INF + (s << 2);
        srcB[j] = W + (size_t)(o0 + r) * INF + (s << 2);
    }

#define STAGE(BUF, KB)                                                       \
    {                                                                        \
        float* ba_ = &lds_f[(BUF) << 14];                                    \
        float* bb_ = ba_ + 8192;                                             \
        _Pragma("unroll")                                                    \
        for (int j = 0; j < 4; ++j) gll16(srcA[j] + (KB), &ba_[dstf[j]]);    \
        _Pragma("unroll")                                                    \
        for (int j = 0; j < 4; ++j) gll16(srcB[j] + (KB), &bb_[dstf[j]]);    \
    }

    f32x4 acc[4][8] = {};

    STAGE(0, 0)
    asm volatile("s_waitcnt vmcnt(0)" ::: "memory");
    __builtin_amdgcn_s_barrier();

    for (int kt = 0; kt < 32; ++kt) {
        if (kt < 31) {
            STAGE((kt + 1) & 1, (kt + 1) << 5);
            // the 8 just-issued DMAs may remain in flight; the 8 oldest
            // (current buffer, issued last iter) must have landed.
            asm volatile("s_waitcnt vmcnt(8)" ::: "memory");
        } else {
            asm volatile("s_waitcnt vmcnt(0)" ::: "memory");
        }
        __builtin_amdgcn_s_barrier();
        asm volatile("" ::: "memory");

        const float* ba = &lds_f[(kt & 1) << 14];
        const float* bb = ba + 8192;

        short8 av[4], bv[8];
#pragma unroll
        for (int mi = 0; mi < 4; ++mi) {
            const int r  = (wr << 6) + (mi << 4) + r0;
            const int s0 = (lg << 1) ^ (r & 7);
            const f32x4 u0 = *(const f32x4*)&ba[(r << 5) + (s0 << 2)];
            const f32x4 u1 = *(const f32x4*)&ba[(r << 5) + ((s0 ^ 1) << 2)];
            short8 h;
#pragma unroll
            for (int j = 0; j < 4; ++j) { h[j] = f2bf(u0[j]); h[4 + j] = f2bf(u1[j]); }
            av[mi] = h;
        }
#pragma unroll
        for (int ni = 0; ni < 8; ++ni) {
            const int r  = (wc << 7) + (ni << 4) + r0;
            const int s0 = (lg << 1) ^ (r & 7);
            const f32x4 u0 = *(const f32x4*)&bb[(r << 5) + (s0 << 2)];
            const f32x4 u1 = *(const f32x4*)&bb[(r << 5) + ((s0 ^ 1) << 2)];
            short8 h;
#pragma unroll
            for (int j = 0; j < 4; ++j) { h[j] = f2bf(u0[j]); h[4 + j] = f2bf(u1[j]); }
            bv[ni] = h;
        }
        __builtin_amdgcn_s_setprio(1);
#pragma unroll
        for (int mi = 0; mi < 4; ++mi)
#pragma unroll
            for (int ni = 0; ni < 8; ++ni)
                acc[mi][ni] = __builtin_amdgcn_mfma_f32_16x16x32_bf16(
                    av[mi], bv[ni], acc[mi][ni], 0, 0, 0);
        __builtin_amdgcn_s_setprio(0);

        // end barrier: all waves done READING buf[cur] before next iter's
        // STAGE overwrites it. ds_reads already consumed by MFMAs (lgkm-by-
        // use); no vmcnt drain here — in-flight DMAs cross this barrier.
        asm volatile("" ::: "memory");
        __builtin_amdgcn_sched_barrier(0);
        __builtin_amdgcn_s_barrier();
    }

    // ---- epilogue: 2 passes of 128 rows; acc -> LDS bf16 (stride 264) ->
    //      coalesced short8 global stores.
    short* cs = (short*)lds_f;
#pragma unroll
    for (int pass = 0; pass < 2; ++pass) {
        if ((wr >> 1) == pass) {
#pragma unroll
            for (int ni = 0; ni < 8; ++ni) {
                const int col = (wc << 7) + (ni << 4) + r0;
                const float bbv = bias[o0 + col];
#pragma unroll
                for (int mi = 0; mi < 4; ++mi) {
                    const int lr = ((wr & 1) << 6) + (mi << 4) + (lg << 2);
#pragma unroll
                    for (int j = 0; j < 4; ++j)
                        cs[(lr + j) * 264 + col] = f2bf(acc[mi][ni][j] + bbv);
                }
            }
        }
        __syncthreads();
        short* cg = (short*)C;
#pragma unroll
        for (int sw = 0; sw < 8; ++sw) {
            const int row = (sw << 4) + (tid >> 5);
            const int gr  = tid & 31;
            short8 v = *(const short8*)&cs[row * 264 + (gr << 3)];
            *(short8*)&cg[(size_t)(m0 + (pass << 7) + row) * OUTF + o0 + (gr << 3)] = v;
        }
        if (pass == 0) __syncthreads();
    }
#undef STAGE
}

// ---------------------------------------------------------------------------
// Scan: u_t = d*u_{t-1} + (1-d)*c_t, segmented (8 segs of 128) with 128-step
// warm-up (d^128 ~ 1.7e-3). cur is bf16. One thread per (b, seg, o).
// ---------------------------------------------------------------------------
template <bool WRITE_OUT>
__global__ __launch_bounds__(256) void scan_kernel(
    const __hip_bfloat16* __restrict__ cur, float* __restrict__ outp,
    float* __restrict__ states, const float* __restrict__ decay) {
    const int gid = blockIdx.x * 256 + threadIdx.x;
    const int o   = gid & 511;
    const int seg = (gid >> 9) & 7;
    const int b   = gid >> 12;

    const float d   = decay[o];
    const float omd = 1.0f - d;
    const __hip_bfloat16* c = cur + (size_t)b * (SEQT * OUTF) + o;
    float* sp = states + (size_t)b * ((SEQT + 1) * OUTF) + o;

    if (seg == 0) sp[0] = 0.0f;

    float u = 0.0f;
    const int t0 = seg << 7;
    const int tw = (seg == 0) ? 0 : (t0 - 128);
    for (int t = tw; t < t0; t += 8) {   // warm-up (no stores)
        float r[8];
#pragma unroll
        for (int j = 0; j < 8; ++j) r[j] = __bfloat162float(c[(size_t)(t + j) * OUTF]);
#pragma unroll
        for (int j = 0; j < 8; ++j) u = fmaf(d, u, omd * r[j]);
    }
    float* op = outp + (size_t)b * (SEQT * OUTF) + o;
    for (int t = t0; t < t0 + 128; t += 8) {
        float r[8];
#pragma unroll
        for (int j = 0; j < 8; ++j) r[j] = __bfloat162float(c[(size_t)(t + j) * OUTF]);
        float uu[8];
#pragma unroll
        for (int j = 0; j < 8; ++j) { u = fmaf(d, u, omd * r[j]); uu[j] = u; }
#pragma unroll
        for (int j = 0; j < 8; ++j) sp[(size_t)(t + 1 + j) * OUTF] = uu[j];
        if (WRITE_OUT) {
#pragma unroll
            for (int j = 0; j < 8; ++j) op[(size_t)(t + j) * OUTF] = uu[j];
        }
    }
}

// outputs[b,t,o] = states[b,t+1,o]  (fallback path only)
__global__ __launch_bounds__(256) void copy_out_kernel(
    float* __restrict__ outp, const float* __restrict__ states) {
    const size_t total = (size_t)MROWS * OUTF / 4;
    size_t i = (size_t)blockIdx.x * blockDim.x + threadIdx.x;
    const size_t stride = (size_t)gridDim.x * blockDim.x;
    for (; i < total; i += stride) {
        const size_t flat = i * 4;
        const size_t o  = flat & 511;
        const size_t bt = flat >> 9;
        const size_t b  = bt >> 10;
        const size_t t  = bt & 1023;
        *(f32x4*)&outp[flat] =
            *(const f32x4*)&states[(b * (SEQT + 1) + t + 1) * OUTF + o];
    }
}

extern "C" void kernel_launch(void* const* d_in, const int* in_sizes, int n_in,
                              void* d_out, int out_size, void* d_ws, size_t ws_size,
                              hipStream_t stream) {
    const float* x     = (const float*)d_in[0];
    const float* w     = (const float*)d_in[1];
    const float* bias  = (const float*)d_in[2];
    const float* decay = (const float*)d_in[3];

    float* outp   = (float*)d_out;
    float* states = outp + (size_t)MROWS * OUTF;   // [B, T+1, OUT] flat

    const size_t cur_bytes = (size_t)MROWS * OUTF * sizeof(__hip_bfloat16);  // 32 MB
    const bool use_ws = (ws_size >= cur_bytes);
    __hip_bfloat16* cur = use_ws ? (__hip_bfloat16*)d_ws : (__hip_bfloat16*)outp;

    gemm_bf16_kernel<<<dim3(256), dim3(512), 0, stream>>>(x, w, bias, cur);

    if (use_ws) {
        scan_kernel<true><<<dim3(512), dim3(256), 0, stream>>>(cur, outp, states, decay);
    } else {
        scan_kernel<false><<<dim3(512), dim3(256), 0, stream>>>(cur, nullptr, states, decay);
        copy_out_kernel<<<dim3(2048), dim3(256), 0, stream>>>(outp, states);
    }
}

// Round 7
// 105.202 us; speedup vs baseline: 1.0671x; 1.0671x over previous
//
#include <hip/hip_runtime.h>
#include <hip/hip_bf16.h>
#include <stdint.h>

#define BATCH 32
#define SEQT  1024
#define INF   1024
#define OUTF  512
#define MROWS (BATCH * SEQT)   // 32768

typedef __attribute__((ext_vector_type(8))) short short8;
typedef __attribute__((ext_vector_type(4))) float f32x4;

__device__ __forceinline__ short f2bf(float f) {
    return (short)__builtin_bit_cast(unsigned short, __float2bfloat16(f));
}

// Swizzled offset (in shorts) of the 16B granule (row r, slot s) in a
// [256][32] bf16 tile packed as 128-line x 128B. Two rows share a line;
// slot' = (s | ((r&1)<<2)) ^ (line&7). 8 consecutive lanes (write side) or
// 8 fragment rows (read side) cover all 8 slots of distinct/same lines ->
// all 32 banks per 8 lanes -> conflict-free b128 on BOTH sides.
__device__ __forceinline__ int swzoff(int r, int s) {
    const int line = r >> 1;
    const int sl = (s | ((r & 1) << 2)) ^ (line & 7);
    return (line << 6) + (sl << 3);
}

// ---------------------------------------------------------------------------
// GEMM: cur[m,o] = bf16( sum_k X[m,k]*W[o,k] + bias[o] )
// 256x256 tile, BK=32, 512 threads (4x2 waves of 64x128), grid=256=1/CU.
// bf16 LDS (halves LDS-read traffic vs R5/R6's fp32-DMA): reg-stage fp32,
// cvt_pk->bf16, swizzled ds_write. T14 within-iteration hiding:
//   issue loads(kt+1) | ds_read+MFMA(buf cur) | cvt+ds_write(buf cur^1) | bar
// sched_barrier(0) fences pin phase order (stop cvt/vmcnt hoisting above
// MFMA). __syncthreads drains nothing extra (no outstanding vmem at barrier).
// ---------------------------------------------------------------------------
__global__ __launch_bounds__(512, 2) void gemm_bf16_kernel(
    const float* __restrict__ X, const float* __restrict__ W,
    const float* __restrict__ bias, __hip_bfloat16* __restrict__ C) {
    // K-loop view: 2 bufs x (A 8192 sh | B 8192 sh) = 32768 shorts (64 KB).
    // Epilogue view: 128 x 264 shorts = 33792. Union-sized (67.6 KB).
    __shared__ short lds_s[33792];

    const int tid = threadIdx.x;
    const int bid = blockIdx.x;
    // XCD pairing: xcd = bid&7 gets 16 m-tiles x both n-tiles (X rows L2-shared).
    const int xcd = bid & 7;
    const int ii  = bid >> 3;
    const int mt  = (xcd << 4) + (ii >> 1);
    const int nt  = ii & 1;
    const int m0 = mt << 8;
    const int o0 = nt << 8;

    const int wv   = tid >> 6;
    const int lane = tid & 63;
    const int wr = wv >> 1;       // 0..3 (64-row slab)
    const int wc = wv & 1;        // 0..1 (128-col slab)
    const int r0 = lane & 15;
    const int lg = lane >> 4;

    // staging: bf16-granule g = j*512+tid (j=0,1): row r=g>>2, slot s=g&3;
    // fp32 source = 32B at X[m0+r][kb + s*8]. Fully coalesced (4 lanes/row).
    int gdst[2];
    const float* gA[2];
    const float* gB[2];
#pragma unroll
    for (int j = 0; j < 2; ++j) {
        const int g = (j << 9) + tid;
        const int r = g >> 2;
        const int s = g & 3;
        gdst[j] = swzoff(r, s);
        gA[j] = X + (size_t)(m0 + r) * INF + (s << 3);
        gB[j] = W + (size_t)(o0 + r) * INF + (s << 3);
    }

    f32x4 sA[2][2], sB[2][2];

#define ISSUE_LOADS(KB)                                                      \
    _Pragma("unroll")                                                        \
    for (int j = 0; j < 2; ++j) {                                            \
        sA[j][0] = *(const f32x4*)(gA[j] + (KB));                            \
        sA[j][1] = *(const f32x4*)(gA[j] + (KB) + 4);                        \
        sB[j][0] = *(const f32x4*)(gB[j] + (KB));                            \
        sB[j][1] = *(const f32x4*)(gB[j] + (KB) + 4);                        \
    }

#define CVT_WRITE(BUF)                                                       \
    {                                                                        \
        short* la_ = &lds_s[(BUF) << 14];                                    \
        short* lb_ = la_ + 8192;                                             \
        _Pragma("unroll")                                                    \
        for (int j = 0; j < 2; ++j) {                                        \
            short8 ha, hb;                                                   \
            _Pragma("unroll")                                                \
            for (int q = 0; q < 4; ++q) {                                    \
                ha[q] = f2bf(sA[j][0][q]); ha[4 + q] = f2bf(sA[j][1][q]);    \
                hb[q] = f2bf(sB[j][0][q]); hb[4 + q] = f2bf(sB[j][1][q]);    \
            }                                                                \
            *(short8*)&la_[gdst[j]] = ha;                                    \
            *(short8*)&lb_[gdst[j]] = hb;                                    \
        }                                                                    \
    }

    f32x4 acc[4][8] = {};

    ISSUE_LOADS(0)
    CVT_WRITE(0)
    __syncthreads();

    for (int kt = 0; kt < 32; ++kt) {
        const int cur = kt & 1;
        // phase 1: issue next tile's global loads (consumed after MFMA)
        if (kt < 31) { ISSUE_LOADS((kt + 1) << 5) }
        __builtin_amdgcn_sched_barrier(0);

        // phase 2: fragments + MFMA from buf[cur]
        const short* la = &lds_s[cur << 14];
        const short* lb = la + 8192;
        short8 av[4], bv[8];
#pragma unroll
        for (int mi = 0; mi < 4; ++mi)
            av[mi] = *(const short8*)&la[swzoff((wr << 6) + (mi << 4) + r0, lg)];
#pragma unroll
        for (int ni = 0; ni < 8; ++ni)
            bv[ni] = *(const short8*)&lb[swzoff((wc << 7) + (ni << 4) + r0, lg)];

        __builtin_amdgcn_s_setprio(1);
#pragma unroll
        for (int mi = 0; mi < 4; ++mi)
#pragma unroll
            for (int ni = 0; ni < 8; ++ni)
                acc[mi][ni] = __builtin_amdgcn_mfma_f32_16x16x32_bf16(
                    av[mi], bv[ni], acc[mi][ni], 0, 0, 0);
        __builtin_amdgcn_s_setprio(0);
        __builtin_amdgcn_sched_barrier(0);

        // phase 3: cvt (compiler inserts vmcnt-by-use) + write other buffer
        if (kt < 31) { CVT_WRITE(cur ^ 1) }
        __syncthreads();
    }
#undef ISSUE_LOADS
#undef CVT_WRITE

    // ---- epilogue: 2 passes of 128 rows; acc -> LDS bf16 (stride 264) ->
    //      coalesced short8 global stores.
    short* cs = lds_s;
#pragma unroll
    for (int pass = 0; pass < 2; ++pass) {
        if ((wr >> 1) == pass) {
#pragma unroll
            for (int ni = 0; ni < 8; ++ni) {
                const int col = (wc << 7) + (ni << 4) + r0;
                const float bbv = bias[o0 + col];
#pragma unroll
                for (int mi = 0; mi < 4; ++mi) {
                    const int lr = ((wr & 1) << 6) + (mi << 4) + (lg << 2);
#pragma unroll
                    for (int j = 0; j < 4; ++j)
                        cs[(lr + j) * 264 + col] = f2bf(acc[mi][ni][j] + bbv);
                }
            }
        }
        __syncthreads();
        short* cg = (short*)C;
#pragma unroll
        for (int sw = 0; sw < 8; ++sw) {
            const int row = (sw << 4) + (tid >> 5);
            const int gr  = tid & 31;
            short8 v = *(const short8*)&cs[row * 264 + (gr << 3)];
            *(short8*)&cg[(size_t)(m0 + (pass << 7) + row) * OUTF + o0 + (gr << 3)] = v;
        }
        if (pass == 0) __syncthreads();
    }
}

// ---------------------------------------------------------------------------
// Scan: u_t = d*u_{t-1} + (1-d)*c_t, segmented (8 segs of 128) with 128-step
// warm-up (d^128 ~ 1.7e-3). cur is bf16. One thread per (b, seg, o).
// ---------------------------------------------------------------------------
template <bool WRITE_OUT>
__global__ __launch_bounds__(256) void scan_kernel(
    const __hip_bfloat16* __restrict__ cur, float* __restrict__ outp,
    float* __restrict__ states, const float* __restrict__ decay) {
    const int gid = blockIdx.x * 256 + threadIdx.x;
    const int o   = gid & 511;
    const int seg = (gid >> 9) & 7;
    const int b   = gid >> 12;

    const float d   = decay[o];
    const float omd = 1.0f - d;
    const __hip_bfloat16* c = cur + (size_t)b * (SEQT * OUTF) + o;
    float* sp = states + (size_t)b * ((SEQT + 1) * OUTF) + o;

    if (seg == 0) sp[0] = 0.0f;

    float u = 0.0f;
    const int t0 = seg << 7;
    const int tw = (seg == 0) ? 0 : (t0 - 128);
    for (int t = tw; t < t0; t += 8) {   // warm-up (no stores)
        float r[8];
#pragma unroll
        for (int j = 0; j < 8; ++j) r[j] = __bfloat162float(c[(size_t)(t + j) * OUTF]);
#pragma unroll
        for (int j = 0; j < 8; ++j) u = fmaf(d, u, omd * r[j]);
    }
    float* op = outp + (size_t)b * (SEQT * OUTF) + o;
    for (int t = t0; t < t0 + 128; t += 8) {
        float r[8];
#pragma unroll
        for (int j = 0; j < 8; ++j) r[j] = __bfloat162float(c[(size_t)(t + j) * OUTF]);
        float uu[8];
#pragma unroll
        for (int j = 0; j < 8; ++j) { u = fmaf(d, u, omd * r[j]); uu[j] = u; }
#pragma unroll
        for (int j = 0; j < 8; ++j) sp[(size_t)(t + 1 + j) * OUTF] = uu[j];
        if (WRITE_OUT) {
#pragma unroll
            for (int j = 0; j < 8; ++j) op[(size_t)(t + j) * OUTF] = uu[j];
        }
    }
}

// outputs[b,t,o] = states[b,t+1,o]  (fallback path only)
__global__ __launch_bounds__(256) void copy_out_kernel(
    float* __restrict__ outp, const float* __restrict__ states) {
    const size_t total = (size_t)MROWS * OUTF / 4;
    size_t i = (size_t)blockIdx.x * blockDim.x + threadIdx.x;
    const size_t stride = (size_t)gridDim.x * blockDim.x;
    for (; i < total; i += stride) {
        const size_t flat = i * 4;
        const size_t o  = flat & 511;
        const size_t bt = flat >> 9;
        const size_t b  = bt >> 10;
        const size_t t  = bt & 1023;
        *(f32x4*)&outp[flat] =
            *(const f32x4*)&states[(b * (SEQT + 1) + t + 1) * OUTF + o];
    }
}

extern "C" void kernel_launch(void* const* d_in, const int* in_sizes, int n_in,
                              void* d_out, int out_size, void* d_ws, size_t ws_size,
                              hipStream_t stream) {
    const float* x     = (const float*)d_in[0];
    const float* w     = (const float*)d_in[1];
    const float* bias  = (const float*)d_in[2];
    const float* decay = (const float*)d_in[3];

    float* outp   = (float*)d_out;
    float* states = outp + (size_t)MROWS * OUTF;   // [B, T+1, OUT] flat

    const size_t cur_bytes = (size_t)MROWS * OUTF * sizeof(__hip_bfloat16);  // 32 MB
    const bool use_ws = (ws_size >= cur_bytes);
    __hip_bfloat16* cur = use_ws ? (__hip_bfloat16*)d_ws : (__hip_bfloat16*)outp;

    gemm_bf16_kernel<<<dim3(256), dim3(512), 0, stream>>>(x, w, bias, cur);

    if (use_ws) {
        scan_kernel<true><<<dim3(512), dim3(256), 0, stream>>>(cur, outp, states, decay);
    } else {
        scan_kernel<false><<<dim3(512), dim3(256), 0, stream>>>(cur, nullptr, states, decay);
        copy_out_kernel<<<dim3(2048), dim3(256), 0, stream>>>(outp, states);
    }
}